// Round 2
// baseline (4399.780 us; speedup 1.0000x reference)
//
#include <hip/hip_runtime.h>
#include <math.h>

constexpr int B_ = 32, N_ = 67, D_ = 128, H_ = 8, DH_ = 16, L_ = 3;
constexpr int NN_ = N_ * N_;          // 4489
constexpr int RN_ = B_ * N_;          // 2144
constexpr int RE_ = B_ * NN_;         // 143648
constexpr int DOUT_ = 10;

__device__ __forceinline__ float gelu_f(float x) {
  return 0.5f * x * (1.f + erff(x * 0.70710678118654752f));
}

// ---------------- precompute: combined weights (Wao@Wl0, We1@Wel0) ----------------
__global__ void k_comb(const float* __restrict__ Wao, const float* __restrict__ bao,
                       const float* __restrict__ Wl0, const float* __restrict__ bl0,
                       const float* __restrict__ We1, const float* __restrict__ be1,
                       const float* __restrict__ Wel0, const float* __restrict__ bel0,
                       float* WcN, float* bcN, float* WcE, float* bcE) {
  int t = blockIdx.x * blockDim.x + threadIdx.x;
  const int half = L_ * D_ * D_;
  if (t >= 2 * half) return;
  int which = t / half;
  int u = t - which * half;
  int l = u / (D_ * D_);
  int ij = u - l * (D_ * D_);
  int i = ij >> 7, j = ij & 127;
  const float* A  = (which == 0 ? Wao : We1) + (size_t)l * D_ * D_;
  const float* Bm = (which == 0 ? Wl0 : Wel0) + (size_t)l * D_ * D_;
  float s = 0.f;
  for (int k = 0; k < D_; k++) s += A[i * D_ + k] * Bm[k * D_ + j];
  if (which == 0) WcN[u] = s; else WcE[u] = s;
  if (i == 0) {
    const float* ba = (which == 0 ? bao : be1) + l * D_;
    const float* bl = (which == 0 ? bl0 : bel0) + l * D_;
    float sb = 0.f;
    for (int k = 0; k < D_; k++) sb += ba[k] * Bm[k * D_ + j];
    if (which == 0) bcN[l * D_ + j] = sb + bl[j]; else bcE[l * D_ + j] = sb + bl[j];
  }
}

// ---------------- precompute: folded input-embed vectors ----------------
__global__ void k_vecs(const float* pbW, const float* pbb, const float* niW, const float* nib,
                       const float* pwW, const float* pwb, const float* eiW, const float* eib,
                       float* vecs) {
  int j = threadIdx.x;
  if (j >= D_) return;
  float u = 0, c = 0, v = 0, ce = 0;
  for (int k = 0; k < D_; k++) {
    u  += pbW[k] * niW[k * D_ + j];
    c  += pbb[k] * niW[k * D_ + j];
    v  += pwW[k] * eiW[k * D_ + j];
    ce += pwb[k] * eiW[k * D_ + j];
  }
  vecs[j] = u; vecs[D_ + j] = c + nib[j]; vecs[2 * D_ + j] = v; vecs[3 * D_ + j] = ce + eib[j];
}

// ---------------- init node / edge ----------------
__global__ void k_init_node(const float* __restrict__ b0, const float* __restrict__ b1,
                            const float* __restrict__ b2, const float* __restrict__ vecs,
                            const float* __restrict__ pos, float* __restrict__ node) {
  int idx = blockIdx.x * blockDim.x + threadIdx.x;
  if (idx >= RN_ * D_) return;
  int r = idx >> 7, d = idx & 127;
  int b = r / N_, n = r - b * N_;
  float nf = 0.f;
  if (n >= 2 && n < 34)       nf = b0[b * 32 + n - 2];
  else if (n >= 34 && n < 66) nf = b1[b * 32 + n - 34];
  else if (n == 66)           nf = b2[b];
  int pr = (n == 0) ? 0 : (n == 1) ? 1 : (n < 34) ? 2 : (n < 66) ? 3 : 4;
  node[idx] = nf * vecs[d] + vecs[D_ + d] + pos[pr * D_ + d];
}

__global__ void k_init_edge(const float* __restrict__ w0, const float* __restrict__ w1,
                            const float* __restrict__ w2, const float* __restrict__ vecs,
                            float* __restrict__ edge) {
  int idx = blockIdx.x * blockDim.x + threadIdx.x;
  if (idx >= RE_ * D_) return;
  int r = idx >> 7, d = idx & 127;
  int b = r / NN_;
  int rem = r - b * NN_;
  int n = rem / N_, m = rem - n * N_;
  float ef = 0.f;
  if (n < 2)        { if (m >= 2 && m < 34)  ef = w0[(b * 2 + n) * 32 + (m - 2)]; }
  else if (n < 34)  { if (m >= 34 && m < 66) ef = w1[(b * 32 + (n - 2)) * 32 + (m - 34)]; }
  else if (n < 66)  { if (m == 66)           ef = w2[b * 32 + (n - 34)]; }
  edge[idx] = ef * vecs[2 * D_ + d] + vecs[3 * D_ + d];
}

// ---------------- LayerNorm (full output) for node rows ----------------
__global__ void k_ln(const float* __restrict__ in, float* __restrict__ out,
                     const float* __restrict__ g, const float* __restrict__ b, int R) {
  int row = blockIdx.x * 4 + (threadIdx.x >> 6);
  int lane = threadIdx.x & 63;
  if (row >= R) return;
  const float* x = in + (size_t)row * D_;
  float x0 = x[lane], x1 = x[lane + 64];
  float s = x0 + x1;
  for (int off = 32; off; off >>= 1) s += __shfl_xor(s, off);
  float mean = s * (1.f / 128.f);
  float d0 = x0 - mean, d1 = x1 - mean;
  float v = d0 * d0 + d1 * d1;
  for (int off = 32; off; off >>= 1) v += __shfl_xor(v, off);
  float rstd = rsqrtf(v * (1.f / 128.f) + 1e-5f);
  out[(size_t)row * D_ + lane]      = d0 * rstd * g[lane] + b[lane];
  out[(size_t)row * D_ + lane + 64] = d1 * rstd * g[lane + 64] + b[lane + 64];
}

// ---------------- per-row LN stats (mu, rstd) for edge rows ----------------
__global__ void k_stats(const float* __restrict__ e, float* __restrict__ stats, int R) {
  int row = blockIdx.x * 4 + (threadIdx.x >> 6);
  int lane = threadIdx.x & 63;
  if (row >= R) return;
  const float* x = e + (size_t)row * D_;
  float x0 = x[lane], x1 = x[lane + 64];
  float s = x0 + x1;
  for (int o = 32; o; o >>= 1) s += __shfl_xor(s, o);
  float mean = s * (1.f / 128.f);
  float d0 = x0 - mean, d1 = x1 - mean;
  float v = d0 * d0 + d1 * d1;
  for (int o = 32; o; o >>= 1) v += __shfl_xor(v, o);
  if (lane == 0) {
    stats[2 * (size_t)row] = mean;
    stats[2 * (size_t)row + 1] = rsqrtf(v * (1.f / 128.f) + 1e-5f);
  }
}

// edge += delta (own rows), then stats of the result
__global__ void k_stats2w(float* __restrict__ edge, const float* __restrict__ delta,
                          float* __restrict__ stats, int R) {
  int row = blockIdx.x * 4 + (threadIdx.x >> 6);
  int lane = threadIdx.x & 63;
  if (row >= R) return;
  size_t base = (size_t)row * D_;
  float x0 = edge[base + lane] + delta[base + lane];
  float x1 = edge[base + lane + 64] + delta[base + lane + 64];
  edge[base + lane] = x0;
  edge[base + lane + 64] = x1;
  float s = x0 + x1;
  for (int o = 32; o; o >>= 1) s += __shfl_xor(s, o);
  float mean = s * (1.f / 128.f);
  float d0 = x0 - mean, d1 = x1 - mean;
  float v = d0 * d0 + d1 * d1;
  for (int o = 32; o; o >>= 1) v += __shfl_xor(v, o);
  if (lane == 0) {
    stats[2 * (size_t)row] = mean;
    stats[2 * (size_t)row + 1] = rsqrtf(v * (1.f / 128.f) + 1e-5f);
  }
}

// ---------------- generic f32 GEMM with ld/col-guard ----------------
// MODE 0: store, 1: gelu-store, 2: add into out
template <int MODE>
__global__ __launch_bounds__(256) void k_gemm(const float* __restrict__ A, const float* __restrict__ W,
                                              const float* __restrict__ bias, float* __restrict__ out,
                                              int R, int K, int C, int ldw, int ldo) {
  __shared__ float As[16][68];
  __shared__ float Wsh[16][68];
  int r0 = blockIdx.x * 64, c0 = blockIdx.y * 64;
  int tid = threadIdx.x;
  int tr = tid >> 4, tc = tid & 15;
  float acc[4][4] = {};
  for (int kk = 0; kk < K; kk += 16) {
#pragma unroll
    for (int i = 0; i < 4; i++) {
      int lin = tid + i * 256;
      int r_in = lin >> 4, k_in = lin & 15;
      int r = r0 + r_in;
      As[k_in][r_in] = (r < R) ? A[(size_t)r * K + kk + k_in] : 0.f;
    }
#pragma unroll
    for (int i = 0; i < 4; i++) {
      int lin = tid + i * 256;
      int k_in = lin >> 6, c_in = lin & 63;
      int c = c0 + c_in;
      Wsh[k_in][c_in] = (c < C) ? W[(size_t)(kk + k_in) * ldw + c] : 0.f;
    }
    __syncthreads();
#pragma unroll
    for (int k = 0; k < 16; k++) {
      float4 a4 = *reinterpret_cast<const float4*>(&As[k][tr * 4]);
      float4 b4 = *reinterpret_cast<const float4*>(&Wsh[k][tc * 4]);
      float av[4] = {a4.x, a4.y, a4.z, a4.w};
      float bv[4] = {b4.x, b4.y, b4.z, b4.w};
#pragma unroll
      for (int i = 0; i < 4; i++)
#pragma unroll
        for (int j = 0; j < 4; j++) acc[i][j] += av[i] * bv[j];
    }
    __syncthreads();
  }
#pragma unroll
  for (int i = 0; i < 4; i++) {
    int r = r0 + tr * 4 + i;
    if (r >= R) continue;
#pragma unroll
    for (int j = 0; j < 4; j++) {
      int c = c0 + tc * 4 + j;
      if (c >= C) continue;
      float v = acc[i][j] + (bias ? bias[c] : 0.f);
      size_t o = (size_t)r * ldo + c;
      if (MODE == 0) out[o] = v;
      else if (MODE == 1) out[o] = gelu_f(v);
      else out[o] += v;
    }
  }
}

// ---------------- attention for a head-pair: slice sl is RE x 96 ----------------
__global__ __launch_bounds__(256) void k_attn2(const float* __restrict__ qkvn,
                                               const float* __restrict__ sl,
                                               float* __restrict__ obuf, int h0) {
  int bn = blockIdx.x;
  int b = bn / N_;
  int tid = threadIdx.x;
  __shared__ float sc[2][68];
  __shared__ float qn_s[2][16];
  __shared__ float red[2][16][8];
  if (tid < 32) {
    int h2 = tid >> 4, d = tid & 15;
    qn_s[h2][d] = qkvn[(size_t)bn * 384 + (h0 + h2) * 48 + d];
  }
  __syncthreads();
  if (tid < 134) {
    int h2 = tid >= 67 ? 1 : 0;
    int m = tid - h2 * 67;
    const float* e = sl + ((size_t)bn * N_ + m) * 96 + h2 * 48;
    const float* kn = qkvn + ((size_t)(b * N_ + m)) * 384 + (h0 + h2) * 48 + 16;
    float s = 0.f;
#pragma unroll
    for (int d = 0; d < DH_; d++) s += (qn_s[h2][d] + e[d]) * (kn[d] + e[16 + d]);
    sc[h2][m] = s * 0.25f;
  }
  __syncthreads();
  {
    int w = tid >> 6, lane = tid & 63;
    if (w < 2) {
      float v0 = (lane < 67) ? sc[w][lane] : -1e30f;
      float v1 = (lane < 3) ? sc[w][lane + 64] : -1e30f;
      float mx = fmaxf(v0, v1);
      for (int o = 32; o; o >>= 1) mx = fmaxf(mx, __shfl_xor(mx, o));
      float e0 = (lane < 67) ? expf(v0 - mx) : 0.f;
      float e1 = (lane < 3) ? expf(v1 - mx) : 0.f;
      float s = e0 + e1;
      for (int o = 32; o; o >>= 1) s += __shfl_xor(s, o);
      float inv = 1.f / s;
      if (lane < 67) sc[w][lane] = e0 * inv;
      if (lane < 3) sc[w][lane + 64] = e1 * inv;
    }
  }
  __syncthreads();
  {
    int h2 = tid >> 7, rest = tid & 127;
    int d = rest >> 3, c = rest & 7;
    float p = 0.f;
    for (int m = c; m < N_; m += 8) {
      float v = qkvn[((size_t)(b * N_ + m)) * 384 + (h0 + h2) * 48 + 32 + d]
              + sl[((size_t)bn * N_ + m) * 96 + h2 * 48 + 32 + d];
      p += sc[h2][m] * v;
    }
    red[h2][d][c] = p;
  }
  __syncthreads();
  if (tid < 32) {
    int h2 = tid >> 4, d = tid & 15;
    float s = 0.f;
#pragma unroll
    for (int c = 0; c < 8; c++) s += red[h2][d][c];
    obuf[(size_t)bn * D_ + (h0 + h2) * 16 + d] = s;
  }
}

// ---------------- row / col means of LN(edge) on the fly ----------------
__global__ void k_rowmean(const float* __restrict__ edge, const float* __restrict__ stats,
                          const float* __restrict__ g, const float* __restrict__ bb,
                          float* __restrict__ rmean) {
  int bn = blockIdx.x;
  int b = bn / N_, n = bn - b * N_;
  int d = threadIdx.x;
  size_t base = (size_t)b * NN_ + (size_t)n * N_;
  float s = 0.f;
  for (int m = 0; m < N_; m++) {
    size_t r = base + m;
    s += (edge[r * D_ + d] - stats[2 * r]) * stats[2 * r + 1];
  }
  rmean[(size_t)bn * D_ + d] = g[d] * (s * (1.f / 67.f)) + bb[d];
}

__global__ void k_colmean(const float* __restrict__ edge, const float* __restrict__ stats,
                          const float* __restrict__ g, const float* __restrict__ bb,
                          float* __restrict__ cmean) {
  int bm = blockIdx.x;
  int b = bm / N_, m = bm - b * N_;
  int d = threadIdx.x;
  float s = 0.f;
  for (int n = 0; n < N_; n++) {
    size_t r = (size_t)b * NN_ + (size_t)n * N_ + m;
    s += (edge[r * D_ + d] - stats[2 * r]) * stats[2 * r + 1];
  }
  cmean[(size_t)bm * D_ + d] = g[d] * (s * (1.f / 67.f)) + bb[d];
}

// ---------------- fused m-block: delta = gelu(concat(en,enT)@We + rvec + cvec) @ WcE + bcE ----------------
__global__ __launch_bounds__(256) void k_medge(
    const float* __restrict__ edge, const float* __restrict__ stats,
    const float* __restrict__ g, const float* __restrict__ bb,
    const float* __restrict__ We, const float* __restrict__ rvec, const float* __restrict__ cvec,
    const float* __restrict__ WcE, const float* __restrict__ bcE,
    float* __restrict__ delta) {
  __shared__ float As[16][68];
  __shared__ float Wsh[16][68];
  __shared__ float mt[64][132];
  int r0 = blockIdx.x * 64;
  int tid = threadIdx.x;
  int tr = tid >> 4, tc = tid & 15;
  unsigned rowA[4], rowT[4];
  float muA[4], rsA[4], muT[4], rsT[4];
  bool val[4];
#pragma unroll
  for (int i = 0; i < 4; i++) {
    int sr = (tid + i * 256) >> 4;
    int gr = r0 + sr;
    val[i] = gr < RE_;
    int grc = val[i] ? gr : 0;
    int b = grc / NN_;
    int rem = grc - b * NN_;
    int n = rem / N_, m = rem - n * N_;
    rowA[i] = (unsigned)grc * 128u;
    unsigned rt = (unsigned)(b * NN_ + m * N_ + n);
    rowT[i] = rt * 128u;
    muA[i] = stats[2 * (size_t)grc]; rsA[i] = stats[2 * (size_t)grc + 1];
    muT[i] = stats[2 * (size_t)rt];  rsT[i] = stats[2 * (size_t)rt + 1];
  }
  int orow[4], ob[4], on[4], om[4];
#pragma unroll
  for (int i = 0; i < 4; i++) {
    int gr2 = r0 + tr * 4 + i;
    orow[i] = gr2;
    int grc = (gr2 < RE_) ? gr2 : 0;
    int b = grc / NN_;
    int rem = grc - b * NN_;
    ob[i] = b; on[i] = rem / N_; om[i] = rem - on[i] * N_;
  }
  // phase 1: mt = gelu(concat @ We + rvec + cvec)
  for (int ch = 0; ch < 2; ch++) {
    float acc[4][4] = {};
    for (int kk = 0; kk < 256; kk += 16) {
#pragma unroll
      for (int i = 0; i < 4; i++) {
        int lin = tid + i * 256;
        int sk = lin & 15, sr = lin >> 4;
        int k = kk + sk;
        float v = 0.f;
        if (val[i]) {
          if (k < 128) v = (edge[rowA[i] + k] - muA[i]) * rsA[i] * g[k] + bb[k];
          else { int k2 = k - 128; v = (edge[rowT[i] + k2] - muT[i]) * rsT[i] * g[k2] + bb[k2]; }
        }
        As[sk][sr] = v;
      }
#pragma unroll
      for (int i = 0; i < 4; i++) {
        int lin = tid + i * 256;
        int wk = lin >> 6, wc = lin & 63;
        Wsh[wk][wc] = We[(size_t)(kk + wk) * 128 + ch * 64 + wc];
      }
      __syncthreads();
#pragma unroll
      for (int k = 0; k < 16; k++) {
        float4 a4 = *reinterpret_cast<const float4*>(&As[k][tr * 4]);
        float4 b4 = *reinterpret_cast<const float4*>(&Wsh[k][tc * 4]);
        float av[4] = {a4.x, a4.y, a4.z, a4.w};
        float bv[4] = {b4.x, b4.y, b4.z, b4.w};
#pragma unroll
        for (int i = 0; i < 4; i++)
#pragma unroll
          for (int j = 0; j < 4; j++) acc[i][j] += av[i] * bv[j];
      }
      __syncthreads();
    }
#pragma unroll
    for (int i = 0; i < 4; i++) {
#pragma unroll
      for (int j = 0; j < 4; j++) {
        int c = ch * 64 + tc * 4 + j;
        float v = 0.f;
        if (orow[i] < RE_) {
          v = acc[i][j] + rvec[(size_t)(ob[i] * N_ + on[i]) * 128 + c]
                        + cvec[(size_t)(ob[i] * N_ + om[i]) * 128 + c];
          v = gelu_f(v);
        }
        mt[tr * 4 + i][c] = v;
      }
    }
    __syncthreads();
  }
  // phase 2: delta = mt @ WcE + bcE
  for (int ch2 = 0; ch2 < 2; ch2++) {
    float acc[4][4] = {};
    for (int kk = 0; kk < 128; kk += 16) {
#pragma unroll
      for (int i = 0; i < 4; i++) {
        int lin = tid + i * 256;
        int wk = lin >> 6, wc = lin & 63;
        Wsh[wk][wc] = WcE[(size_t)(kk + wk) * 128 + ch2 * 64 + wc];
      }
      __syncthreads();
#pragma unroll
      for (int k = 0; k < 16; k++) {
        float4 b4 = *reinterpret_cast<const float4*>(&Wsh[k][tc * 4]);
        float bv[4] = {b4.x, b4.y, b4.z, b4.w};
        float av[4];
#pragma unroll
        for (int i = 0; i < 4; i++) av[i] = mt[tr * 4 + i][kk + k];
#pragma unroll
        for (int i = 0; i < 4; i++)
#pragma unroll
          for (int j = 0; j < 4; j++) acc[i][j] += av[i] * bv[j];
      }
      __syncthreads();
    }
#pragma unroll
    for (int i = 0; i < 4; i++) {
      if (orow[i] >= RE_) continue;
#pragma unroll
      for (int j = 0; j < 4; j++) {
        int c = ch2 * 64 + tc * 4 + j;
        delta[(size_t)orow[i] * 128 + c] = acc[i][j] + bcE[c];
      }
    }
  }
}

// ---------------- fused edge MLP: edge += gelu(LN(edge)@mW1+mb1)@mW2+mb2 ----------------
__global__ __launch_bounds__(256) void k_mlpedge(
    float* __restrict__ edge, const float* __restrict__ stats,
    const float* __restrict__ g, const float* __restrict__ bb,
    const float* __restrict__ mW1, const float* __restrict__ mb1,
    const float* __restrict__ mW2, const float* __restrict__ mb2) {
  __shared__ float As[16][68];
  __shared__ float Wsh[16][68];
  __shared__ float mt[64][132];
  int r0 = blockIdx.x * 64;
  int tid = threadIdx.x;
  int tr = tid >> 4, tc = tid & 15;
  unsigned rowA[4];
  float muA[4], rsA[4];
  bool val[4];
#pragma unroll
  for (int i = 0; i < 4; i++) {
    int sr = (tid + i * 256) >> 4;
    int gr = r0 + sr;
    val[i] = gr < RE_;
    int grc = val[i] ? gr : 0;
    rowA[i] = (unsigned)grc * 128u;
    muA[i] = stats[2 * (size_t)grc]; rsA[i] = stats[2 * (size_t)grc + 1];
  }
  float acc2[2][4][4] = {};
  for (int h = 0; h < 2; h++) {
    // phase 1: mt = gelu(LN(edge) @ mW1[:, h*128 : h*128+128] + mb1)
    for (int ch = 0; ch < 2; ch++) {
      float acc[4][4] = {};
      for (int kk = 0; kk < 128; kk += 16) {
#pragma unroll
        for (int i = 0; i < 4; i++) {
          int lin = tid + i * 256;
          int sk = lin & 15, sr = lin >> 4;
          int k = kk + sk;
          float v = 0.f;
          if (val[i]) v = (edge[rowA[i] + k] - muA[i]) * rsA[i] * g[k] + bb[k];
          As[sk][sr] = v;
        }
#pragma unroll
        for (int i = 0; i < 4; i++) {
          int lin = tid + i * 256;
          int wk = lin >> 6, wc = lin & 63;
          Wsh[wk][wc] = mW1[(size_t)(kk + wk) * 256 + h * 128 + ch * 64 + wc];
        }
        __syncthreads();
#pragma unroll
        for (int k = 0; k < 16; k++) {
          float4 a4 = *reinterpret_cast<const float4*>(&As[k][tr * 4]);
          float4 b4 = *reinterpret_cast<const float4*>(&Wsh[k][tc * 4]);
          float av[4] = {a4.x, a4.y, a4.z, a4.w};
          float bv[4] = {b4.x, b4.y, b4.z, b4.w};
#pragma unroll
          for (int i = 0; i < 4; i++)
#pragma unroll
            for (int j = 0; j < 4; j++) acc[i][j] += av[i] * bv[j];
        }
        __syncthreads();
      }
#pragma unroll
      for (int i = 0; i < 4; i++)
#pragma unroll
        for (int j = 0; j < 4; j++) {
          int c = ch * 64 + tc * 4 + j;
          mt[tr * 4 + i][c] = gelu_f(acc[i][j] + mb1[h * 128 + c]);
        }
      __syncthreads();
    }
    // phase 2: acc2 += mt @ mW2[h*128 : h*128+128, :]
    for (int ch2 = 0; ch2 < 2; ch2++) {
      for (int kk = 0; kk < 128; kk += 16) {
#pragma unroll
        for (int i = 0; i < 4; i++) {
          int lin = tid + i * 256;
          int wk = lin >> 6, wc = lin & 63;
          Wsh[wk][wc] = mW2[(size_t)(h * 128 + kk + wk) * 128 + ch2 * 64 + wc];
        }
        __syncthreads();
#pragma unroll
        for (int k = 0; k < 16; k++) {
          float4 b4 = *reinterpret_cast<const float4*>(&Wsh[k][tc * 4]);
          float bv[4] = {b4.x, b4.y, b4.z, b4.w};
          float av[4];
#pragma unroll
          for (int i = 0; i < 4; i++) av[i] = mt[tr * 4 + i][kk + k];
#pragma unroll
          for (int i = 0; i < 4; i++)
#pragma unroll
            for (int j = 0; j < 4; j++) acc2[ch2][i][j] += av[i] * bv[j];
        }
        __syncthreads();
      }
    }
  }
#pragma unroll
  for (int i = 0; i < 4; i++) {
    int gr2 = r0 + tr * 4 + i;
    if (gr2 >= RE_) continue;
#pragma unroll
    for (int ch2 = 0; ch2 < 2; ch2++)
#pragma unroll
      for (int j = 0; j < 4; j++) {
        int c = ch2 * 64 + tc * 4 + j;
        edge[(size_t)gr2 * 128 + c] += acc2[ch2][i][j] + mb2[c];
      }
  }
}

// ---------------- head ----------------
__global__ void k_head(const float* __restrict__ node, const float* __restrict__ Wo1,
                       const float* __restrict__ bo1, const float* __restrict__ Wo2,
                       const float* __restrict__ bo2, float* __restrict__ out) {
  int b = blockIdx.x;
  int tid = threadIdx.x;  // 128
  __shared__ float gsh[D_];
  __shared__ float h1[D_];
  float s = 0.f;
  for (int n = 0; n < N_; n++) s += node[((size_t)b * N_ + n) * D_ + tid];
  gsh[tid] = s * (1.f / 67.f);
  __syncthreads();
  float a = 0.f;
  for (int k = 0; k < D_; k++) a += gsh[k] * Wo1[k * D_ + tid];
  h1[tid] = fmaxf(a + bo1[tid], 0.f);
  __syncthreads();
  if (tid < DOUT_) {
    float r = 0.f;
    for (int k = 0; k < D_; k++) r += h1[k] * Wo2[k * DOUT_ + tid];
    out[b * DOUT_ + tid] = r + bo2[tid];
  }
}

// ---------------- host ----------------
extern "C" void kernel_launch(void* const* d_in, const int* in_sizes, int n_in,
                              void* d_out, int out_size, void* d_ws, size_t ws_size,
                              hipStream_t stream) {
  const float* w0   = (const float*)d_in[0];
  const float* w1   = (const float*)d_in[1];
  const float* w2   = (const float*)d_in[2];
  const float* b0   = (const float*)d_in[3];
  const float* b1   = (const float*)d_in[4];
  const float* b2   = (const float*)d_in[5];
  const float* pwW  = (const float*)d_in[6];
  const float* pwb  = (const float*)d_in[7];
  const float* pbW  = (const float*)d_in[8];
  const float* pbb  = (const float*)d_in[9];
  const float* niW  = (const float*)d_in[10];
  const float* nib  = (const float*)d_in[11];
  const float* eiW  = (const float*)d_in[12];
  const float* eib  = (const float*)d_in[13];
  const float* pos  = (const float*)d_in[14];
  const float* alng = (const float*)d_in[15];
  const float* alnb = (const float*)d_in[16];
  const float* Wqkvn= (const float*)d_in[17];
  const float* Wqkve= (const float*)d_in[18];
  const float* Wao  = (const float*)d_in[19];
  const float* bao  = (const float*)d_in[20];
  const float* Wl0  = (const float*)d_in[21];
  const float* bl0  = (const float*)d_in[22];
  const float* nlng = (const float*)d_in[23];
  const float* nlnb = (const float*)d_in[24];
  const float* nW1  = (const float*)d_in[25];
  const float* nb1  = (const float*)d_in[26];
  const float* nW2  = (const float*)d_in[27];
  const float* nb2  = (const float*)d_in[28];
  const float* elng = (const float*)d_in[29];
  const float* elnb = (const float*)d_in[30];
  const float* We   = (const float*)d_in[31];
  const float* be   = (const float*)d_in[32];
  const float* Ws   = (const float*)d_in[33];
  const float* bs   = (const float*)d_in[34];
  const float* Wt   = (const float*)d_in[35];
  const float* bt   = (const float*)d_in[36];
  const float* Wer  = (const float*)d_in[37];
  const float* Wec  = (const float*)d_in[38];
  const float* We1  = (const float*)d_in[39];
  const float* be1  = (const float*)d_in[40];
  const float* Wel0 = (const float*)d_in[41];
  const float* bel0 = (const float*)d_in[42];
  const float* mlng = (const float*)d_in[43];
  const float* mlnb = (const float*)d_in[44];
  const float* mW1  = (const float*)d_in[45];
  const float* mb1  = (const float*)d_in[46];
  const float* mW2  = (const float*)d_in[47];
  const float* mb2  = (const float*)d_in[48];
  const float* Wo1  = (const float*)d_in[49];
  const float* bo1  = (const float*)d_in[50];
  const float* Wo2  = (const float*)d_in[51];
  const float* bo2  = (const float*)d_in[52];
  float* outp = (float*)d_out;

  const size_t E = (size_t)RE_ * D_;      // 18,386,944
  const size_t NODE = (size_t)RN_ * D_;   // 274,432
  const int DD = D_ * D_;

  float* ws = (float*)d_ws;
  size_t off = 0;
  auto alloc = [&](size_t nf) { float* p = ws + off; off += nf; return p; };
  float* edge  = alloc(E);
  float* escr  = alloc(E);                 // qkv_e head-pair slices (RE x 96) / m-delta (RE x 128)
  float* stats = alloc(2 * (size_t)RE_);
  float* node  = alloc(NODE);
  float* h_ln  = alloc(NODE);
  float* qkvn  = alloc(3 * NODE);
  float* obuf  = alloc(NODE);
  float* t_n   = alloc(2 * NODE);
  float* rmean = alloc(NODE);
  float* cmean = alloc(NODE);
  float* rvec  = alloc(NODE);
  float* cvec  = alloc(NODE);
  float* WcN   = alloc((size_t)L_ * DD);
  float* bcN   = alloc((size_t)L_ * D_);
  float* WcE   = alloc((size_t)L_ * DD);
  float* bcE   = alloc((size_t)L_ * D_);
  float* vecs  = alloc(4 * D_);
  (void)ws_size; (void)in_sizes; (void)n_in; (void)out_size;

  // precompute
  k_comb<<<(2 * L_ * DD + 255) / 256, 256, 0, stream>>>(Wao, bao, Wl0, bl0, We1, be1, Wel0, bel0,
                                                        WcN, bcN, WcE, bcE);
  k_vecs<<<1, 128, 0, stream>>>(pbW, pbb, niW, nib, pwW, pwb, eiW, eib, vecs);
  k_init_node<<<(RN_ * D_ + 255) / 256, 256, 0, stream>>>(b0, b1, b2, vecs, pos, node);
  k_init_edge<<<(int)((E + 255) / 256), 256, 0, stream>>>(w0, w1, w2, vecs, edge);

  const int GE = (RE_ + 63) / 64;  // 2245
  const int GN = (RN_ + 63) / 64;  // 34
  const int GSE = (RE_ + 3) / 4;
  const int GSN = (RN_ + 3) / 4;

  for (int l = 0; l < L_; l++) {
    const float* Wqn = Wqkvn + (size_t)l * D_ * 384;
    const float* Wqe = Wqkve + (size_t)l * D_ * 384;

    // --- attention (uses pre-update edge) ---
    k_ln<<<GSN, 256, 0, stream>>>(node, h_ln, alng + l * D_, alnb + l * D_, RN_);
    k_gemm<0><<<dim3(GN, 6), 256, 0, stream>>>(h_ln, Wqn, nullptr, qkvn, RN_, 128, 384, 384, 384);
    for (int hg = 0; hg < 4; hg++) {
      k_gemm<0><<<dim3(GE, 2), 256, 0, stream>>>(edge, Wqe + hg * 96, nullptr, escr,
                                                 RE_, 128, 96, 384, 96);
      k_attn2<<<RN_, 256, 0, stream>>>(qkvn, escr, obuf, 2 * hg);
    }
    k_gemm<2><<<dim3(GN, 2), 256, 0, stream>>>(obuf, WcN + (size_t)l * DD, bcN + l * D_, node,
                                               RN_, 128, 128, 128, 128);

    // --- node MLP ---
    k_ln<<<GSN, 256, 0, stream>>>(node, h_ln, nlng + l * D_, nlnb + l * D_, RN_);
    k_gemm<1><<<dim3(GN, 4), 256, 0, stream>>>(h_ln, nW1 + (size_t)l * D_ * 256, nb1 + l * 256, t_n,
                                               RN_, 128, 256, 256, 256);
    k_gemm<2><<<dim3(GN, 2), 256, 0, stream>>>(t_n, nW2 + (size_t)l * 256 * D_, nb2 + l * D_, node,
                                               RN_, 256, 128, 128, 128);

    // --- edge m-block ---
    k_stats<<<GSE, 256, 0, stream>>>(edge, stats, RE_);
    k_rowmean<<<RN_, 128, 0, stream>>>(edge, stats, elng + l * D_, elnb + l * D_, rmean);
    k_colmean<<<RN_, 128, 0, stream>>>(edge, stats, elng + l * D_, elnb + l * D_, cmean);
    k_gemm<0><<<dim3(GN, 2), 256, 0, stream>>>(node, Ws + (size_t)l * DD, bs + l * D_, rvec,
                                               RN_, 128, 128, 128, 128);
    k_gemm<2><<<dim3(GN, 2), 256, 0, stream>>>(rmean, Wer + (size_t)l * DD, be + l * D_, rvec,
                                               RN_, 128, 128, 128, 128);
    k_gemm<0><<<dim3(GN, 2), 256, 0, stream>>>(node, Wt + (size_t)l * DD, bt + l * D_, cvec,
                                               RN_, 128, 128, 128, 128);
    k_gemm<2><<<dim3(GN, 2), 256, 0, stream>>>(cmean, Wec + (size_t)l * DD, nullptr, cvec,
                                               RN_, 128, 128, 128, 128);
    k_medge<<<GE, 256, 0, stream>>>(edge, stats, elng + l * D_, elnb + l * D_,
                                    We + (size_t)l * 256 * D_, rvec, cvec,
                                    WcE + (size_t)l * DD, bcE + l * D_, escr);
    k_stats2w<<<GSE, 256, 0, stream>>>(edge, escr, stats, RE_);

    // --- edge MLP (in-place, own rows only) ---
    k_mlpedge<<<GE, 256, 0, stream>>>(edge, stats, mlng + l * D_, mlnb + l * D_,
                                      mW1 + (size_t)l * D_ * 256, mb1 + l * 256,
                                      mW2 + (size_t)l * 256 * D_, mb2 + l * D_);
  }

  k_head<<<B_, 128, 0, stream>>>(node, Wo1, bo1, Wo2, bo2, outp);
}

// Round 3
// 2327.851 us; speedup vs baseline: 1.8901x; 1.8901x over previous
//
#include <hip/hip_runtime.h>
#include <math.h>

constexpr int B_ = 32, N_ = 67, D_ = 128, H_ = 8, DH_ = 16, L_ = 3;
constexpr int NN_ = N_ * N_;          // 4489
constexpr int RN_ = B_ * N_;          // 2144
constexpr int RE_ = B_ * NN_;         // 143648
constexpr int DOUT_ = 10;

typedef __attribute__((ext_vector_type(8))) short short8;
typedef __attribute__((ext_vector_type(4))) float f32x4;

__device__ __forceinline__ float gelu_f(float x) {
  return 0.5f * x * (1.f + erff(x * 0.70710678118654752f));
}

__device__ __forceinline__ ushort f2b(float x) {
  union { float f; unsigned u; } v; v.f = x;
  return (ushort)((v.u + 0x7FFFu + ((v.u >> 16) & 1u)) >> 16);
}

// ---------------- precompute: combined weights (Wao@Wl0, We1@Wel0) ----------------
__global__ void k_comb(const float* __restrict__ Wao, const float* __restrict__ bao,
                       const float* __restrict__ Wl0, const float* __restrict__ bl0,
                       const float* __restrict__ We1, const float* __restrict__ be1,
                       const float* __restrict__ Wel0, const float* __restrict__ bel0,
                       float* WcN, float* bcN, float* WcE, float* bcE) {
  int t = blockIdx.x * blockDim.x + threadIdx.x;
  const int half = L_ * D_ * D_;
  if (t >= 2 * half) return;
  int which = t / half;
  int u = t - which * half;
  int l = u / (D_ * D_);
  int ij = u - l * (D_ * D_);
  int i = ij >> 7, j = ij & 127;
  const float* A  = (which == 0 ? Wao : We1) + (size_t)l * D_ * D_;
  const float* Bm = (which == 0 ? Wl0 : Wel0) + (size_t)l * D_ * D_;
  float s = 0.f;
  for (int k = 0; k < D_; k++) s += A[i * D_ + k] * Bm[k * D_ + j];
  if (which == 0) WcN[u] = s; else WcE[u] = s;
  if (i == 0) {
    const float* ba = (which == 0 ? bao : be1) + l * D_;
    const float* bl = (which == 0 ? bl0 : bel0) + l * D_;
    float sb = 0.f;
    for (int k = 0; k < D_; k++) sb += ba[k] * Bm[k * D_ + j];
    if (which == 0) bcN[l * D_ + j] = sb + bl[j]; else bcE[l * D_ + j] = sb + bl[j];
  }
}

// ---------------- precompute: folded input-embed vectors ----------------
__global__ void k_vecs(const float* pbW, const float* pbb, const float* niW, const float* nib,
                       const float* pwW, const float* pwb, const float* eiW, const float* eib,
                       float* vecs) {
  int j = threadIdx.x;
  if (j >= D_) return;
  float u = 0, c = 0, v = 0, ce = 0;
  for (int k = 0; k < D_; k++) {
    u  += pbW[k] * niW[k * D_ + j];
    c  += pbb[k] * niW[k * D_ + j];
    v  += pwW[k] * eiW[k * D_ + j];
    ce += pwb[k] * eiW[k * D_ + j];
  }
  vecs[j] = u; vecs[D_ + j] = c + nib[j]; vecs[2 * D_ + j] = v; vecs[3 * D_ + j] = ce + eib[j];
}

// ---------------- init node / edge ----------------
__global__ void k_init_node(const float* __restrict__ b0, const float* __restrict__ b1,
                            const float* __restrict__ b2, const float* __restrict__ vecs,
                            const float* __restrict__ pos, float* __restrict__ node) {
  int idx = blockIdx.x * blockDim.x + threadIdx.x;
  if (idx >= RN_ * D_) return;
  int r = idx >> 7, d = idx & 127;
  int b = r / N_, n = r - b * N_;
  float nf = 0.f;
  if (n >= 2 && n < 34)       nf = b0[b * 32 + n - 2];
  else if (n >= 34 && n < 66) nf = b1[b * 32 + n - 34];
  else if (n == 66)           nf = b2[b];
  int pr = (n == 0) ? 0 : (n == 1) ? 1 : (n < 34) ? 2 : (n < 66) ? 3 : 4;
  node[idx] = nf * vecs[d] + vecs[D_ + d] + pos[pr * D_ + d];
}

__global__ void k_init_edge(const float* __restrict__ w0, const float* __restrict__ w1,
                            const float* __restrict__ w2, const float* __restrict__ vecs,
                            float* __restrict__ edge) {
  int idx = blockIdx.x * blockDim.x + threadIdx.x;
  if (idx >= RE_ * D_) return;
  int r = idx >> 7, d = idx & 127;
  int b = r / NN_;
  int rem = r - b * NN_;
  int n = rem / N_, m = rem - n * N_;
  float ef = 0.f;
  if (n < 2)        { if (m >= 2 && m < 34)  ef = w0[(b * 2 + n) * 32 + (m - 2)]; }
  else if (n < 34)  { if (m >= 34 && m < 66) ef = w1[(b * 32 + (n - 2)) * 32 + (m - 34)]; }
  else if (n < 66)  { if (m == 66)           ef = w2[b * 32 + (n - 34)]; }
  edge[idx] = ef * vecs[2 * D_ + d] + vecs[3 * D_ + d];
}

// ---------------- LayerNorm (full output) for node rows ----------------
__global__ void k_ln(const float* __restrict__ in, float* __restrict__ out,
                     const float* __restrict__ g, const float* __restrict__ b, int R) {
  int row = blockIdx.x * 4 + (threadIdx.x >> 6);
  int lane = threadIdx.x & 63;
  if (row >= R) return;
  const float* x = in + (size_t)row * D_;
  float x0 = x[lane], x1 = x[lane + 64];
  float s = x0 + x1;
  for (int off = 32; off; off >>= 1) s += __shfl_xor(s, off);
  float mean = s * (1.f / 128.f);
  float d0 = x0 - mean, d1 = x1 - mean;
  float v = d0 * d0 + d1 * d1;
  for (int off = 32; off; off >>= 1) v += __shfl_xor(v, off);
  float rstd = rsqrtf(v * (1.f / 128.f) + 1e-5f);
  out[(size_t)row * D_ + lane]      = d0 * rstd * g[lane] + b[lane];
  out[(size_t)row * D_ + lane + 64] = d1 * rstd * g[lane + 64] + b[lane + 64];
}

// ---------------- per-row LN stats (mu, rstd) for edge rows ----------------
__global__ void k_stats(const float* __restrict__ e, float* __restrict__ stats, int R) {
  int row = blockIdx.x * 4 + (threadIdx.x >> 6);
  int lane = threadIdx.x & 63;
  if (row >= R) return;
  const float* x = e + (size_t)row * D_;
  float x0 = x[lane], x1 = x[lane + 64];
  float s = x0 + x1;
  for (int o = 32; o; o >>= 1) s += __shfl_xor(s, o);
  float mean = s * (1.f / 128.f);
  float d0 = x0 - mean, d1 = x1 - mean;
  float v = d0 * d0 + d1 * d1;
  for (int o = 32; o; o >>= 1) v += __shfl_xor(v, o);
  if (lane == 0) {
    stats[2 * (size_t)row] = mean;
    stats[2 * (size_t)row + 1] = rsqrtf(v * (1.f / 128.f) + 1e-5f);
  }
}

// edge += delta (own rows), then stats of the result
__global__ void k_stats2w(float* __restrict__ edge, const float* __restrict__ delta,
                          float* __restrict__ stats, int R) {
  int row = blockIdx.x * 4 + (threadIdx.x >> 6);
  int lane = threadIdx.x & 63;
  if (row >= R) return;
  size_t base = (size_t)row * D_;
  float x0 = edge[base + lane] + delta[base + lane];
  float x1 = edge[base + lane + 64] + delta[base + lane + 64];
  edge[base + lane] = x0;
  edge[base + lane + 64] = x1;
  float s = x0 + x1;
  for (int o = 32; o; o >>= 1) s += __shfl_xor(s, o);
  float mean = s * (1.f / 128.f);
  float d0 = x0 - mean, d1 = x1 - mean;
  float v = d0 * d0 + d1 * d1;
  for (int o = 32; o; o >>= 1) v += __shfl_xor(v, o);
  if (lane == 0) {
    stats[2 * (size_t)row] = mean;
    stats[2 * (size_t)row + 1] = rsqrtf(v * (1.f / 128.f) + 1e-5f);
  }
}

// ---------------- generic f32 SIMT GEMM (node-side, small) ----------------
// MODE 0: store, 1: gelu-store, 2: add into out
template <int MODE>
__global__ __launch_bounds__(256) void k_gemm(const float* __restrict__ A, const float* __restrict__ W,
                                              const float* __restrict__ bias, float* __restrict__ out,
                                              int R, int K, int C, int ldw, int ldo) {
  __shared__ float As[16][68];
  __shared__ float Wsh[16][68];
  int r0 = blockIdx.x * 64, c0 = blockIdx.y * 64;
  int tid = threadIdx.x;
  int tr = tid >> 4, tc = tid & 15;
  float acc[4][4] = {};
  for (int kk = 0; kk < K; kk += 16) {
#pragma unroll
    for (int i = 0; i < 4; i++) {
      int lin = tid + i * 256;
      int r_in = lin >> 4, k_in = lin & 15;
      int r = r0 + r_in;
      As[k_in][r_in] = (r < R) ? A[(size_t)r * K + kk + k_in] : 0.f;
    }
#pragma unroll
    for (int i = 0; i < 4; i++) {
      int lin = tid + i * 256;
      int k_in = lin >> 6, c_in = lin & 63;
      int c = c0 + c_in;
      Wsh[k_in][c_in] = (c < C) ? W[(size_t)(kk + k_in) * ldw + c] : 0.f;
    }
    __syncthreads();
#pragma unroll
    for (int k = 0; k < 16; k++) {
      float4 a4 = *reinterpret_cast<const float4*>(&As[k][tr * 4]);
      float4 b4 = *reinterpret_cast<const float4*>(&Wsh[k][tc * 4]);
      float av[4] = {a4.x, a4.y, a4.z, a4.w};
      float bv[4] = {b4.x, b4.y, b4.z, b4.w};
#pragma unroll
      for (int i = 0; i < 4; i++)
#pragma unroll
        for (int j = 0; j < 4; j++) acc[i][j] += av[i] * bv[j];
    }
    __syncthreads();
  }
#pragma unroll
  for (int i = 0; i < 4; i++) {
    int r = r0 + tr * 4 + i;
    if (r >= R) continue;
#pragma unroll
    for (int j = 0; j < 4; j++) {
      int c = c0 + tc * 4 + j;
      if (c >= C) continue;
      float v = acc[i][j] + (bias ? bias[c] : 0.f);
      size_t o = (size_t)r * ldo + c;
      if (MODE == 0) out[o] = v;
      else if (MODE == 1) out[o] = gelu_f(v);
      else out[o] += v;
    }
  }
}

// ---------------- MFMA bf16 GEMM, K=128 fixed: out = A @ W (no bias) ----------------
__global__ __launch_bounds__(256) void k_gemm_bf16_k128(
    const float* __restrict__ A, const float* __restrict__ W,
    float* __restrict__ out, int R, int C, int ldw, int ldo) {
  __shared__ ushort As[64][136];
  __shared__ ushort Bs[64][136];
  int tid = threadIdx.x;
  int r0 = blockIdx.x * 64;
  int w = tid >> 6, lane = tid & 63;
  int lr = lane & 15, lk8 = (lane >> 4) * 8;
  // stage A (f32 -> bf16)
#pragma unroll
  for (int i = 0; i < 8; i++) {
    int idx = tid + i * 256;
    int row = idx >> 5, c4 = (idx & 31) * 4;
    int r = r0 + row;
    float ax = 0, ay = 0, az = 0, aw = 0;
    if (r < R) {
      float4 a = *reinterpret_cast<const float4*>(&A[(size_t)r * 128 + c4]);
      ax = a.x; ay = a.y; az = a.z; aw = a.w;
    }
    ushort* d = &As[row][c4];
    d[0] = f2b(ax); d[1] = f2b(ay); d[2] = f2b(az); d[3] = f2b(aw);
  }
  int nch = (C + 63) >> 6;
  for (int ch = 0; ch < nch; ch++) {
    __syncthreads();
#pragma unroll
    for (int i = 0; i < 8; i++) {
      int idx = tid + i * 256;
      int k = idx >> 4, c4 = (idx & 15) * 4;
      int c = ch * 64 + c4;
      float bx = 0, by = 0, bz = 0, bw = 0;
      if (c + 3 < C) {
        float4 t = *reinterpret_cast<const float4*>(&W[(size_t)k * ldw + c]);
        bx = t.x; by = t.y; bz = t.z; bw = t.w;
      } else {
        if (c < C)     bx = W[(size_t)k * ldw + c];
        if (c + 1 < C) by = W[(size_t)k * ldw + c + 1];
        if (c + 2 < C) bz = W[(size_t)k * ldw + c + 2];
        if (c + 3 < C) bw = W[(size_t)k * ldw + c + 3];
      }
      Bs[c4 + 0][k] = f2b(bx); Bs[c4 + 1][k] = f2b(by);
      Bs[c4 + 2][k] = f2b(bz); Bs[c4 + 3][k] = f2b(bw);
    }
    __syncthreads();
    f32x4 acc[4] = {{0,0,0,0},{0,0,0,0},{0,0,0,0},{0,0,0,0}};
#pragma unroll
    for (int ks = 0; ks < 4; ks++) {
      int kof = ks * 32 + lk8;
      short8 af = *reinterpret_cast<const short8*>(&As[w * 16 + lr][kof]);
#pragma unroll
      for (int cf = 0; cf < 4; cf++) {
        short8 bfr = *reinterpret_cast<const short8*>(&Bs[cf * 16 + lr][kof]);
        acc[cf] = __builtin_amdgcn_mfma_f32_16x16x32_bf16(af, bfr, acc[cf], 0, 0, 0);
      }
    }
    int rb = (lane >> 4) * 4;
#pragma unroll
    for (int cf = 0; cf < 4; cf++) {
      int c = ch * 64 + cf * 16 + lr;
      if (c >= C) continue;
#pragma unroll
      for (int rg = 0; rg < 4; rg++) {
        int r = r0 + w * 16 + rb + rg;
        if (r < R) out[(size_t)r * ldo + c] = acc[cf][rg];
      }
    }
  }
}

// ---------------- attention for a head-pair: slice sl is RE x 96 ----------------
__global__ __launch_bounds__(256) void k_attn2(const float* __restrict__ qkvn,
                                               const float* __restrict__ sl,
                                               float* __restrict__ obuf, int h0) {
  int bn = blockIdx.x;
  int b = bn / N_;
  int tid = threadIdx.x;
  __shared__ float sc[2][68];
  __shared__ float qn_s[2][16];
  __shared__ float red[2][16][8];
  if (tid < 32) {
    int h2 = tid >> 4, d = tid & 15;
    qn_s[h2][d] = qkvn[(size_t)bn * 384 + (h0 + h2) * 48 + d];
  }
  __syncthreads();
  if (tid < 134) {
    int h2 = tid >= 67 ? 1 : 0;
    int m = tid - h2 * 67;
    const float* e = sl + ((size_t)bn * N_ + m) * 96 + h2 * 48;
    const float* kn = qkvn + ((size_t)(b * N_ + m)) * 384 + (h0 + h2) * 48 + 16;
    float s = 0.f;
#pragma unroll
    for (int d = 0; d < DH_; d++) s += (qn_s[h2][d] + e[d]) * (kn[d] + e[16 + d]);
    sc[h2][m] = s * 0.25f;
  }
  __syncthreads();
  {
    int w = tid >> 6, lane = tid & 63;
    if (w < 2) {
      float v0 = (lane < 67) ? sc[w][lane] : -1e30f;
      float v1 = (lane < 3) ? sc[w][lane + 64] : -1e30f;
      float mx = fmaxf(v0, v1);
      for (int o = 32; o; o >>= 1) mx = fmaxf(mx, __shfl_xor(mx, o));
      float e0 = (lane < 67) ? expf(v0 - mx) : 0.f;
      float e1 = (lane < 3) ? expf(v1 - mx) : 0.f;
      float s = e0 + e1;
      for (int o = 32; o; o >>= 1) s += __shfl_xor(s, o);
      float inv = 1.f / s;
      if (lane < 67) sc[w][lane] = e0 * inv;
      if (lane < 3) sc[w][lane + 64] = e1 * inv;
    }
  }
  __syncthreads();
  {
    int h2 = tid >> 7, rest = tid & 127;
    int d = rest >> 3, c = rest & 7;
    float p = 0.f;
    for (int m = c; m < N_; m += 8) {
      float v = qkvn[((size_t)(b * N_ + m)) * 384 + (h0 + h2) * 48 + 32 + d]
              + sl[((size_t)bn * N_ + m) * 96 + h2 * 48 + 32 + d];
      p += sc[h2][m] * v;
    }
    red[h2][d][c] = p;
  }
  __syncthreads();
  if (tid < 32) {
    int h2 = tid >> 4, d = tid & 15;
    float s = 0.f;
#pragma unroll
    for (int c = 0; c < 8; c++) s += red[h2][d][c];
    obuf[(size_t)bn * D_ + (h0 + h2) * 16 + d] = s;
  }
}

// ---------------- row / col means of LN(edge) on the fly ----------------
__global__ void k_rowmean(const float* __restrict__ edge, const float* __restrict__ stats,
                          const float* __restrict__ g, const float* __restrict__ bb,
                          float* __restrict__ rmean) {
  int bn = blockIdx.x;
  int b = bn / N_, n = bn - b * N_;
  int d = threadIdx.x;
  size_t base = (size_t)b * NN_ + (size_t)n * N_;
  float s = 0.f;
  for (int m = 0; m < N_; m++) {
    size_t r = base + m;
    s += (edge[r * D_ + d] - stats[2 * r]) * stats[2 * r + 1];
  }
  rmean[(size_t)bn * D_ + d] = g[d] * (s * (1.f / 67.f)) + bb[d];
}

__global__ void k_colmean(const float* __restrict__ edge, const float* __restrict__ stats,
                          const float* __restrict__ g, const float* __restrict__ bb,
                          float* __restrict__ cmean) {
  int bm = blockIdx.x;
  int b = bm / N_, m = bm - b * N_;
  int d = threadIdx.x;
  float s = 0.f;
  for (int n = 0; n < N_; n++) {
    size_t r = (size_t)b * NN_ + (size_t)n * N_ + m;
    s += (edge[r * D_ + d] - stats[2 * r]) * stats[2 * r + 1];
  }
  cmean[(size_t)bm * D_ + d] = g[d] * (s * (1.f / 67.f)) + bb[d];
}

// ---------------- fused m-block (MFMA): delta = gelu(concat(en,enT)@We + rvec + cvec) @ WcE + bcE ----------------
__global__ __launch_bounds__(256) void k_medge(
    const float* __restrict__ edge, const float* __restrict__ stats,
    const float* __restrict__ g, const float* __restrict__ bb,
    const float* __restrict__ We, const float* __restrict__ rvec, const float* __restrict__ cvec,
    const float* __restrict__ WcE, const float* __restrict__ bcE,
    float* __restrict__ delta) {
  __shared__ ushort As[64][264];
  __shared__ ushort Bs[64][136];
  __shared__ ushort mt[64][136];
  int tid = threadIdx.x;
  int r0 = blockIdx.x * 64;
  int w = tid >> 6, lane = tid & 63;
  int lr = lane & 15, lk8 = (lane >> 4) * 8;

  // stage A = [LN(edge row) | LN(edgeT row)] as bf16
#pragma unroll
  for (int half = 0; half < 2; half++) {
#pragma unroll
    for (int i = 0; i < 8; i++) {
      int idx = tid + i * 256;
      int row = idx >> 5, c4 = (idx & 31) * 4;
      int gr = r0 + row;
      int grc = (gr < RE_) ? gr : 0;
      size_t srow;
      if (half == 0) srow = (size_t)grc;
      else {
        int b = grc / NN_; int rem = grc - b * NN_;
        int n = rem / N_, m = rem - n * N_;
        srow = (size_t)b * NN_ + (size_t)m * N_ + n;
      }
      float mu = stats[2 * srow], rs = stats[2 * srow + 1];
      float4 a = *reinterpret_cast<const float4*>(&edge[srow * 128 + c4]);
      float4 gg = *reinterpret_cast<const float4*>(&g[c4]);
      float4 bv = *reinterpret_cast<const float4*>(&bb[c4]);
      ushort* dst = &As[row][half * 128 + c4];
      dst[0] = f2b((a.x - mu) * rs * gg.x + bv.x);
      dst[1] = f2b((a.y - mu) * rs * gg.y + bv.y);
      dst[2] = f2b((a.z - mu) * rs * gg.z + bv.z);
      dst[3] = f2b((a.w - mu) * rs * gg.w + bv.w);
    }
  }

  // epilogue row bases
  int rb = (lane >> 4) * 4;
  int rvb[4], cvb[4]; bool vrow[4];
#pragma unroll
  for (int rg = 0; rg < 4; rg++) {
    int gr = r0 + w * 16 + rb + rg;
    vrow[rg] = gr < RE_;
    int grc = vrow[rg] ? gr : 0;
    int b = grc / NN_; int rem = grc - b * NN_;
    int n = rem / N_, m = rem - n * N_;
    rvb[rg] = (b * N_ + n) * 128;
    cvb[rg] = (b * N_ + m) * 128;
  }

  auto stageB = [&](const float* Wp, int kbase, int cbase) {
#pragma unroll
    for (int i = 0; i < 8; i++) {
      int idx = tid + i * 256;
      int k = idx >> 4, c4 = (idx & 15) * 4;
      float4 t = *reinterpret_cast<const float4*>(&Wp[(size_t)(kbase + k) * 128 + cbase + c4]);
      Bs[c4 + 0][k] = f2b(t.x); Bs[c4 + 1][k] = f2b(t.y);
      Bs[c4 + 2][k] = f2b(t.z); Bs[c4 + 3][k] = f2b(t.w);
    }
  };

  // phase 1: mt = gelu(concat @ We + rvec + cvec)   [K=256, C=128]
  for (int ch = 0; ch < 2; ch++) {
    f32x4 acc[4] = {{0,0,0,0},{0,0,0,0},{0,0,0,0},{0,0,0,0}};
    for (int kp = 0; kp < 2; kp++) {
      __syncthreads();
      stageB(We, kp * 128, ch * 64);
      __syncthreads();
#pragma unroll
      for (int ks = 0; ks < 4; ks++) {
        int kof = ks * 32 + lk8;
        short8 af = *reinterpret_cast<const short8*>(&As[w * 16 + lr][kp * 128 + kof]);
#pragma unroll
        for (int cf = 0; cf < 4; cf++) {
          short8 bfr = *reinterpret_cast<const short8*>(&Bs[cf * 16 + lr][kof]);
          acc[cf] = __builtin_amdgcn_mfma_f32_16x16x32_bf16(af, bfr, acc[cf], 0, 0, 0);
        }
      }
    }
#pragma unroll
    for (int cf = 0; cf < 4; cf++) {
      int c = ch * 64 + cf * 16 + lr;
#pragma unroll
      for (int rg = 0; rg < 4; rg++) {
        float v = acc[cf][rg] + rvec[rvb[rg] + c] + cvec[cvb[rg] + c];
        mt[w * 16 + rb + rg][c] = f2b(gelu_f(v));
      }
    }
  }

  // phase 2: delta = mt @ WcE + bcE   [K=128, C=128]
  for (int ch = 0; ch < 2; ch++) {
    __syncthreads();
    stageB(WcE, 0, ch * 64);
    __syncthreads();
    f32x4 acc[4] = {{0,0,0,0},{0,0,0,0},{0,0,0,0},{0,0,0,0}};
#pragma unroll
    for (int ks = 0; ks < 4; ks++) {
      int kof = ks * 32 + lk8;
      short8 af = *reinterpret_cast<const short8*>(&mt[w * 16 + lr][kof]);
#pragma unroll
      for (int cf = 0; cf < 4; cf++) {
        short8 bfr = *reinterpret_cast<const short8*>(&Bs[cf * 16 + lr][kof]);
        acc[cf] = __builtin_amdgcn_mfma_f32_16x16x32_bf16(af, bfr, acc[cf], 0, 0, 0);
      }
    }
#pragma unroll
    for (int cf = 0; cf < 4; cf++) {
      int c = ch * 64 + cf * 16 + lr;
#pragma unroll
      for (int rg = 0; rg < 4; rg++) {
        if (!vrow[rg]) continue;
        int gr = r0 + w * 16 + rb + rg;
        delta[(size_t)gr * 128 + c] = acc[cf][rg] + bcE[c];
      }
    }
  }
}

// ---------------- fused edge MLP (MFMA): edge += gelu(LN(edge)@mW1+mb1)@mW2+mb2 ----------------
__global__ __launch_bounds__(256) void k_mlpedge(
    float* __restrict__ edge, const float* __restrict__ stats,
    const float* __restrict__ g, const float* __restrict__ bb,
    const float* __restrict__ mW1, const float* __restrict__ mb1,
    const float* __restrict__ mW2, const float* __restrict__ mb2) {
  __shared__ ushort As[64][136];
  __shared__ ushort Bs[64][136];
  __shared__ ushort mt[64][264];
  int tid = threadIdx.x;
  int r0 = blockIdx.x * 64;
  int w = tid >> 6, lane = tid & 63;
  int lr = lane & 15, lk8 = (lane >> 4) * 8;

  // stage A = LN(edge) bf16
#pragma unroll
  for (int i = 0; i < 8; i++) {
    int idx = tid + i * 256;
    int row = idx >> 5, c4 = (idx & 31) * 4;
    int gr = r0 + row;
    int grc = (gr < RE_) ? gr : 0;
    float mu = stats[2 * (size_t)grc], rs = stats[2 * (size_t)grc + 1];
    float4 a = *reinterpret_cast<const float4*>(&edge[(size_t)grc * 128 + c4]);
    float4 gg = *reinterpret_cast<const float4*>(&g[c4]);
    float4 bv = *reinterpret_cast<const float4*>(&bb[c4]);
    ushort* dst = &As[row][c4];
    dst[0] = f2b((a.x - mu) * rs * gg.x + bv.x);
    dst[1] = f2b((a.y - mu) * rs * gg.y + bv.y);
    dst[2] = f2b((a.z - mu) * rs * gg.z + bv.z);
    dst[3] = f2b((a.w - mu) * rs * gg.w + bv.w);
  }

  int rb = (lane >> 4) * 4;

  auto stageB = [&](const float* Wp, int ldw2, int kbase, int cbase) {
#pragma unroll
    for (int i = 0; i < 8; i++) {
      int idx = tid + i * 256;
      int k = idx >> 4, c4 = (idx & 15) * 4;
      float4 t = *reinterpret_cast<const float4*>(&Wp[(size_t)(kbase + k) * ldw2 + cbase + c4]);
      Bs[c4 + 0][k] = f2b(t.x); Bs[c4 + 1][k] = f2b(t.y);
      Bs[c4 + 2][k] = f2b(t.z); Bs[c4 + 3][k] = f2b(t.w);
    }
  };

  // phase 1: mt = gelu(LN(edge) @ mW1 + mb1)   [K=128, C=256]
  for (int ch = 0; ch < 4; ch++) {
    __syncthreads();
    stageB(mW1, 256, 0, ch * 64);
    __syncthreads();
    f32x4 acc[4] = {{0,0,0,0},{0,0,0,0},{0,0,0,0},{0,0,0,0}};
#pragma unroll
    for (int ks = 0; ks < 4; ks++) {
      int kof = ks * 32 + lk8;
      short8 af = *reinterpret_cast<const short8*>(&As[w * 16 + lr][kof]);
#pragma unroll
      for (int cf = 0; cf < 4; cf++) {
        short8 bfr = *reinterpret_cast<const short8*>(&Bs[cf * 16 + lr][kof]);
        acc[cf] = __builtin_amdgcn_mfma_f32_16x16x32_bf16(af, bfr, acc[cf], 0, 0, 0);
      }
    }
#pragma unroll
    for (int cf = 0; cf < 4; cf++) {
      int c = ch * 64 + cf * 16 + lr;
#pragma unroll
      for (int rg = 0; rg < 4; rg++)
        mt[w * 16 + rb + rg][c] = f2b(gelu_f(acc[cf][rg] + mb1[c]));
    }
  }

  // phase 2: edge += mt @ mW2 + mb2   [K=256, C=128]
  for (int ch = 0; ch < 2; ch++) {
    f32x4 acc[4] = {{0,0,0,0},{0,0,0,0},{0,0,0,0},{0,0,0,0}};
    for (int kp = 0; kp < 2; kp++) {
      __syncthreads();
      stageB(mW2, 128, kp * 128, ch * 64);
      __syncthreads();
#pragma unroll
      for (int ks = 0; ks < 4; ks++) {
        int kof = ks * 32 + lk8;
        short8 af = *reinterpret_cast<const short8*>(&mt[w * 16 + lr][kp * 128 + kof]);
#pragma unroll
        for (int cf = 0; cf < 4; cf++) {
          short8 bfr = *reinterpret_cast<const short8*>(&Bs[cf * 16 + lr][kof]);
          acc[cf] = __builtin_amdgcn_mfma_f32_16x16x32_bf16(af, bfr, acc[cf], 0, 0, 0);
        }
      }
    }
#pragma unroll
    for (int cf = 0; cf < 4; cf++) {
      int c = ch * 64 + cf * 16 + lr;
#pragma unroll
      for (int rg = 0; rg < 4; rg++) {
        int gr = r0 + w * 16 + rb + rg;
        if (gr < RE_) edge[(size_t)gr * 128 + c] += acc[cf][rg] + mb2[c];
      }
    }
  }
}

// ---------------- head ----------------
__global__ void k_head(const float* __restrict__ node, const float* __restrict__ Wo1,
                       const float* __restrict__ bo1, const float* __restrict__ Wo2,
                       const float* __restrict__ bo2, float* __restrict__ out) {
  int b = blockIdx.x;
  int tid = threadIdx.x;  // 128
  __shared__ float gsh[D_];
  __shared__ float h1[D_];
  float s = 0.f;
  for (int n = 0; n < N_; n++) s += node[((size_t)b * N_ + n) * D_ + tid];
  gsh[tid] = s * (1.f / 67.f);
  __syncthreads();
  float a = 0.f;
  for (int k = 0; k < D_; k++) a += gsh[k] * Wo1[k * D_ + tid];
  h1[tid] = fmaxf(a + bo1[tid], 0.f);
  __syncthreads();
  if (tid < DOUT_) {
    float r = 0.f;
    for (int k = 0; k < D_; k++) r += h1[k] * Wo2[k * DOUT_ + tid];
    out[b * DOUT_ + tid] = r + bo2[tid];
  }
}

// ---------------- host ----------------
extern "C" void kernel_launch(void* const* d_in, const int* in_sizes, int n_in,
                              void* d_out, int out_size, void* d_ws, size_t ws_size,
                              hipStream_t stream) {
  const float* w0   = (const float*)d_in[0];
  const float* w1   = (const float*)d_in[1];
  const float* w2   = (const float*)d_in[2];
  const float* b0   = (const float*)d_in[3];
  const float* b1   = (const float*)d_in[4];
  const float* b2   = (const float*)d_in[5];
  const float* pwW  = (const float*)d_in[6];
  const float* pwb  = (const float*)d_in[7];
  const float* pbW  = (const float*)d_in[8];
  const float* pbb  = (const float*)d_in[9];
  const float* niW  = (const float*)d_in[10];
  const float* nib  = (const float*)d_in[11];
  const float* eiW  = (const float*)d_in[12];
  const float* eib  = (const float*)d_in[13];
  const float* pos  = (const float*)d_in[14];
  const float* alng = (const float*)d_in[15];
  const float* alnb = (const float*)d_in[16];
  const float* Wqkvn= (const float*)d_in[17];
  const float* Wqkve= (const float*)d_in[18];
  const float* Wao  = (const float*)d_in[19];
  const float* bao  = (const float*)d_in[20];
  const float* Wl0  = (const float*)d_in[21];
  const float* bl0  = (const float*)d_in[22];
  const float* nlng = (const float*)d_in[23];
  const float* nlnb = (const float*)d_in[24];
  const float* nW1  = (const float*)d_in[25];
  const float* nb1  = (const float*)d_in[26];
  const float* nW2  = (const float*)d_in[27];
  const float* nb2  = (const float*)d_in[28];
  const float* elng = (const float*)d_in[29];
  const float* elnb = (const float*)d_in[30];
  const float* We   = (const float*)d_in[31];
  const float* be   = (const float*)d_in[32];
  const float* Ws   = (const float*)d_in[33];
  const float* bs   = (const float*)d_in[34];
  const float* Wt   = (const float*)d_in[35];
  const float* bt   = (const float*)d_in[36];
  const float* Wer  = (const float*)d_in[37];
  const float* Wec  = (const float*)d_in[38];
  const float* We1  = (const float*)d_in[39];
  const float* be1  = (const float*)d_in[40];
  const float* Wel0 = (const float*)d_in[41];
  const float* bel0 = (const float*)d_in[42];
  const float* mlng = (const float*)d_in[43];
  const float* mlnb = (const float*)d_in[44];
  const float* mW1  = (const float*)d_in[45];
  const float* mb1  = (const float*)d_in[46];
  const float* mW2  = (const float*)d_in[47];
  const float* mb2  = (const float*)d_in[48];
  const float* Wo1  = (const float*)d_in[49];
  const float* bo1  = (const float*)d_in[50];
  const float* Wo2  = (const float*)d_in[51];
  const float* bo2  = (const float*)d_in[52];
  float* outp = (float*)d_out;

  const size_t E = (size_t)RE_ * D_;      // 18,386,944
  const size_t NODE = (size_t)RN_ * D_;   // 274,432
  const int DD = D_ * D_;

  float* ws = (float*)d_ws;
  size_t off = 0;
  auto alloc = [&](size_t nf) { float* p = ws + off; off += nf; return p; };
  float* edge  = alloc(E);
  float* escr  = alloc(E);                 // qkv_e head-pair slices (RE x 96) / m-delta (RE x 128)
  float* stats = alloc(2 * (size_t)RE_);
  float* node  = alloc(NODE);
  float* h_ln  = alloc(NODE);
  float* qkvn  = alloc(3 * NODE);
  float* obuf  = alloc(NODE);
  float* t_n   = alloc(2 * NODE);
  float* rmean = alloc(NODE);
  float* cmean = alloc(NODE);
  float* rvec  = alloc(NODE);
  float* cvec  = alloc(NODE);
  float* WcN   = alloc((size_t)L_ * DD);
  float* bcN   = alloc((size_t)L_ * D_);
  float* WcE   = alloc((size_t)L_ * DD);
  float* bcE   = alloc((size_t)L_ * D_);
  float* vecs  = alloc(4 * D_);
  (void)ws_size; (void)in_sizes; (void)n_in; (void)out_size;

  // precompute
  k_comb<<<(2 * L_ * DD + 255) / 256, 256, 0, stream>>>(Wao, bao, Wl0, bl0, We1, be1, Wel0, bel0,
                                                        WcN, bcN, WcE, bcE);
  k_vecs<<<1, 128, 0, stream>>>(pbW, pbb, niW, nib, pwW, pwb, eiW, eib, vecs);
  k_init_node<<<(RN_ * D_ + 255) / 256, 256, 0, stream>>>(b0, b1, b2, vecs, pos, node);
  k_init_edge<<<(int)((E + 255) / 256), 256, 0, stream>>>(w0, w1, w2, vecs, edge);

  const int GE = (RE_ + 63) / 64;  // 2245
  const int GN = (RN_ + 63) / 64;  // 34
  const int GSE = (RE_ + 3) / 4;
  const int GSN = (RN_ + 3) / 4;

  for (int l = 0; l < L_; l++) {
    const float* Wqn = Wqkvn + (size_t)l * D_ * 384;
    const float* Wqe = Wqkve + (size_t)l * D_ * 384;

    // --- attention (uses pre-update edge) ---
    k_ln<<<GSN, 256, 0, stream>>>(node, h_ln, alng + l * D_, alnb + l * D_, RN_);
    k_gemm<0><<<dim3(GN, 6), 256, 0, stream>>>(h_ln, Wqn, nullptr, qkvn, RN_, 128, 384, 384, 384);
    for (int hg = 0; hg < 4; hg++) {
      k_gemm_bf16_k128<<<GE, 256, 0, stream>>>(edge, Wqe + hg * 96, escr, RE_, 96, 384, 96);
      k_attn2<<<RN_, 256, 0, stream>>>(qkvn, escr, obuf, 2 * hg);
    }
    k_gemm<2><<<dim3(GN, 2), 256, 0, stream>>>(obuf, WcN + (size_t)l * DD, bcN + l * D_, node,
                                               RN_, 128, 128, 128, 128);

    // --- node MLP ---
    k_ln<<<GSN, 256, 0, stream>>>(node, h_ln, nlng + l * D_, nlnb + l * D_, RN_);
    k_gemm<1><<<dim3(GN, 4), 256, 0, stream>>>(h_ln, nW1 + (size_t)l * D_ * 256, nb1 + l * 256, t_n,
                                               RN_, 128, 256, 256, 256);
    k_gemm<2><<<dim3(GN, 2), 256, 0, stream>>>(t_n, nW2 + (size_t)l * 256 * D_, nb2 + l * D_, node,
                                               RN_, 256, 128, 128, 128);

    // --- edge m-block ---
    k_stats<<<GSE, 256, 0, stream>>>(edge, stats, RE_);
    k_rowmean<<<RN_, 128, 0, stream>>>(edge, stats, elng + l * D_, elnb + l * D_, rmean);
    k_colmean<<<RN_, 128, 0, stream>>>(edge, stats, elng + l * D_, elnb + l * D_, cmean);
    k_gemm<0><<<dim3(GN, 2), 256, 0, stream>>>(node, Ws + (size_t)l * DD, bs + l * D_, rvec,
                                               RN_, 128, 128, 128, 128);
    k_gemm<2><<<dim3(GN, 2), 256, 0, stream>>>(rmean, Wer + (size_t)l * DD, be + l * D_, rvec,
                                               RN_, 128, 128, 128, 128);
    k_gemm<0><<<dim3(GN, 2), 256, 0, stream>>>(node, Wt + (size_t)l * DD, bt + l * D_, cvec,
                                               RN_, 128, 128, 128, 128);
    k_gemm<2><<<dim3(GN, 2), 256, 0, stream>>>(cmean, Wec + (size_t)l * DD, nullptr, cvec,
                                               RN_, 128, 128, 128, 128);
    k_medge<<<GE, 256, 0, stream>>>(edge, stats, elng + l * D_, elnb + l * D_,
                                    We + (size_t)l * 256 * D_, rvec, cvec,
                                    WcE + (size_t)l * DD, bcE + l * D_, escr);
    k_stats2w<<<GSE, 256, 0, stream>>>(edge, escr, stats, RE_);

    // --- edge MLP (in-place, own rows only) ---
    k_mlpedge<<<GE, 256, 0, stream>>>(edge, stats, mlng + l * D_, mlnb + l * D_,
                                      mW1 + (size_t)l * D_ * 256, mb1 + l * 256,
                                      mW2 + (size_t)l * 256 * D_, mb2 + l * D_);
  }

  k_head<<<B_, 128, 0, stream>>>(node, Wo1, bo1, Wo2, bo2, outp);
}